// Round 11
// baseline (4001.844 us; speedup 1.0000x reference)
//
#include <hip/hip_runtime.h>

#define N_NODES 200000
#define N_EDGES 6400000
#define HID 200
#define NREP 8                    // scatter accumulator replicas
#define MT 64                     // nodes per block (3125 * 64 = 200000 exactly)
#define ASTR 232                  // act row stride (fp16): 464 B; 2-way bank alias = free
#define AELEM (MT * ASTR)         // 14848 elems = 29696 B
#define WSTR 232
#define WROWS 224
#define WELEMS (WROWS * WSTR)     // g_wph per-layer elems
#define H0ROWS 112                // half0: tiles 0..6
#define H1ROWS 96                 // half1: tiles 7..12
#define H0CH (H0ROWS * WSTR * 2 / 16)   // 3248 16-B chunks
#define H1CH (H1ROWS * WSTR * 2 / 16)   // 2784 16-B chunks

// LDS: act [0, 29696) ; wlds [29696, 81664) ; h0s aliased at wlds start (dead
// before first stage). 81,664 x 2 blocks = 163,328 <= 163,840 -> 2 blocks/CU.
#define LDS_WOFF 29696
#define LDS_TOTAL 81664

typedef float f32x4 __attribute__((ext_vector_type(4)));
typedef _Float16 f16x8 __attribute__((ext_vector_type(8)));
typedef unsigned short u16;
typedef unsigned int u32;

__device__ __align__(16) float g_agg[NREP * N_NODES];
__device__ __align__(16) float g_xf[N_NODES];            // fp32 copy of x
__device__ __align__(16) float g_wf[6 * HID * HID];      // fp32 (VALU fallback)
__device__ __align__(16) _Float16 g_wph[6 * WELEMS];     // fp16 W^T padded [l][n][k]
__device__ int g_isbf;

__device__ __forceinline__ float bf2f(u16 u) {
  union { u32 i; float f; } v; v.i = ((u32)u) << 16; return v.f;
}
__device__ __forceinline__ u16 f2bf(float f) {  // RNE
  u32 i = __float_as_uint(f);
  return (u16)((i + 0x7FFFu + ((i >> 16) & 1u)) >> 16);
}
__device__ __forceinline__ float ldf(const void* p, int i, int isbf) {
  return isbf ? bf2f(((const u16*)p)[i]) : ((const float*)p)[i];
}
__device__ __forceinline__ void load_lds16(const void* g, void* l) {
  __builtin_amdgcn_global_load_lds(
      (const __attribute__((address_space(1))) u32*)g,
      (__attribute__((address_space(3))) u32*)l, 16, 0, 0);
}

// ---- rank-2 MFMA layout self-test (fp16), reference folded at compile time ----
constexpr int tf1(int m) { return (m & 3) + 1; }
constexpr int tf2(int m) { return ((m >> 2) & 3) + 2; }
constexpr int tg1(int k) { return (k & 7) + 1; }
constexpr int tg2(int k) { return ((k >> 3) & 3) + 1; }
constexpr int tu1(int k) { return ((k * 3) & 7) + 1; }
constexpr int tu2(int k) { return ((k >> 2) & 3) + 2; }
constexpr int tw1(int n) { return ((n * 5) & 7) + 1; }
constexpr int tw2(int n) { return ((n >> 2) & 3) + 1; }
constexpr int calcS(int i, int j) {
  int s = 0;
  for (int k = 0; k < 32; ++k)
    s += (i ? tg2(k) : tg1(k)) * (j ? tu2(k) : tu1(k));
  return s;
}
__device__ __forceinline__ float refD(int m, int n) {
  constexpr int S11 = calcS(0, 0), S12 = calcS(0, 1), S21 = calcS(1, 0), S22 = calcS(1, 1);
  return (float)(tf1(m) * tw1(n) * S11 + tf1(m) * tw2(n) * S12 +
                 tf2(m) * tw1(n) * S21 + tf2(m) * tw2(n) * S22);
}
__device__ int mfma_selftest(int l15, int q) {
  f16x8 av, bv;
#pragma unroll
  for (int j = 0; j < 8; ++j) {
    int k = q * 8 + j;
    av[j] = (_Float16)(float)(tf1(l15) * tg1(k) + tf2(l15) * tg2(k));
    bv[j] = (_Float16)(float)(tu1(k) * tw1(l15) + tu2(k) * tw2(l15));
  }
  f32x4 d = __builtin_amdgcn_mfma_f32_16x16x32_f16(av, bv, (f32x4){0.f, 0.f, 0.f, 0.f}, 0, 0, 0);
  bool ok0 = true, ok1 = true;
#pragma unroll
  for (int r = 0; r < 4; ++r) {
    ok0 = ok0 && (d[r] == refD(q * 4 + r, l15));
    ok1 = ok1 && (d[r] == refD(l15, q * 4 + r));
  }
  return __all(ok0) ? 0 : (__all(ok1) ? 1 : 2);
}

// ---- K0: dtype sniff ----
__global__ void sniff_kernel(const u32* __restrict__ xw) {
  int i = threadIdx.x;  // 64 threads
  u32 e = (xw[i] >> 7) & 0xFFu;
  unsigned long long b = __ballot(e >= 110u && e <= 135u);
  if (i == 0) g_isbf = (__popcll(b) >= 48) ? 1 : 0;
}

// ---- K1: zero replicas + fp32 x + both weight forms ----
__global__ void prep_kernel(const void* __restrict__ x, const void* __restrict__ w_hid) {
  int t = blockIdx.x * blockDim.x + threadIdx.x;   // 1.6M threads
  int isbf = g_isbf;
  if (t < NREP * N_NODES) g_agg[t] = 0.f;
  if (t < N_NODES) g_xf[t] = ldf(x, t, isbf);
  if (t < 6 * HID * HID) g_wf[t] = ldf(w_hid, t, isbf);
  if (t < 6 * WELEMS) {
    int l = t / WELEMS;
    int r = t - l * WELEMS;
    int n = r / WSTR;
    int k = r - n * WSTR;
    float v = 0.f;
    if (n < HID && k < HID) v = ldf(w_hid, (l * HID + k) * HID + n, isbf);
    g_wph[t] = (_Float16)v;
  }
}

// ---- K2: edge scatter-add; 8 edges/thread, batched loads, 8 replicas ----
__global__ void scatter_kernel(const int* __restrict__ ei) {
  int t = blockIdx.x * blockDim.x + threadIdx.x;   // 800K threads
  int e = t * 8;
  float* agg = g_agg + (size_t)(blockIdx.x & (NREP - 1)) * N_NODES;
  bool is64 = ((ei[1] | ei[3] | ei[5] | ei[7]) == 0);
  int s[8], d[8];
  if (is64) {
#pragma unroll
    for (int i = 0; i < 4; ++i) {
      int4 a = *(const int4*)(ei + 2 * e + 4 * i);
      int4 b = *(const int4*)(ei + 2 * N_EDGES + 2 * e + 4 * i);
      s[2 * i] = a.x; s[2 * i + 1] = a.z;
      d[2 * i] = b.x; d[2 * i + 1] = b.z;
    }
  } else {
#pragma unroll
    for (int i = 0; i < 2; ++i) {
      int4 a = *(const int4*)(ei + e + 4 * i);
      int4 b = *(const int4*)(ei + N_EDGES + e + 4 * i);
      s[4 * i] = a.x; s[4 * i + 1] = a.y; s[4 * i + 2] = a.z; s[4 * i + 3] = a.w;
      d[4 * i] = b.x; d[4 * i + 1] = b.y; d[4 * i + 2] = b.z; d[4 * i + 3] = b.w;
    }
  }
  float v[8];
#pragma unroll
  for (int i = 0; i < 8; ++i) v[i] = g_xf[s[i]];
#pragma unroll
  for (int i = 0; i < 8; ++i) atomicAdd(&agg[d[i]], v[i]);
}

// ---- K3: fused MLP; MT=64, 512 thr / 8 waves, W in halves -> 2 blocks/CU ----
__global__ __launch_bounds__(512, 2) void mlp_kernel(
    const void* __restrict__ w_rel, const void* __restrict__ b_rel, const void* __restrict__ w_root,
    const void* __restrict__ w_in, const void* __restrict__ b_in,
    const void* __restrict__ b_hid, const void* __restrict__ w_out, const void* __restrict__ b_out,
    void* __restrict__ out) {
  extern __shared__ char smem[];
  _Float16* act = (_Float16*)smem;
  _Float16* wlds = (_Float16*)(smem + LDS_WOFF);
  float* h0s = (float*)(smem + LDS_WOFF);  // aliased; dead before first stage

  const int tid = threadIdx.x;
  const int nb = blockIdx.x * MT;
  const int isbf = g_isbf;
  const int lane = tid & 63;
  const int wv = tid >> 6;          // 8 waves
  const int l15 = lane & 15;
  const int q = lane >> 4;
  const int band = wv >> 1;         // 4 bands x 16 rows
  const int cg = wv & 1;            // col group: tiles {0-3,7-9} / {4-6,10-12}

  const int mode = mfma_selftest(l15, q);

  // GraphConv h0 (8 replicas summed)
  if (tid < MT) {
    int node = nb + tid;
    float a = 0.f;
#pragma unroll
    for (int r = 0; r < NREP; ++r) a += g_agg[(size_t)r * N_NODES + node];
    h0s[tid] = a * ldf(w_rel, 0, isbf) + ldf(b_rel, 0, isbf) +
               g_xf[node] * ldf(w_root, 0, isbf);
  }
  __syncthreads();

  if (mode < 2) {
    // Input layer: act[m][j] = relu(h0[m]*w_in[j]+b_in[j]); pad cols zeroed
    for (int idx = tid; idx < AELEM; idx += 512) {
      int m = idx / ASTR, j = idx - m * ASTR;
      float v = 0.f;
      if (j < HID) {
        v = h0s[m] * ldf(w_in, j, isbf) + ldf(b_in, j, isbf);
        v = fmaxf(v, 0.f);
      }
      act[idx] = (_Float16)v;
    }

    for (int l = 0; l < 6; ++l) {
      f32x4 acc[7];
#pragma unroll
      for (int n = 0; n < 7; ++n) acc[n] = (f32x4){0.f, 0.f, 0.f, 0.f};

      const _Float16* ap = act + (band * 16 + l15) * ASTR + q * 8;

      // ---- half 0: tiles 0..6 ----
      __syncthreads();  // act stable (epilogue/input), prior wlds reads done
      {
        const _Float16* wg = g_wph + l * WELEMS;
        for (int c = tid; c < H0CH; c += 512) load_lds16(wg + c * 8, wlds + c * 8);
      }
      __syncthreads();  // drain
      {
        const int lb = cg ? 4 : 0;          // local tile base within staged half
        const int cnt = cg ? 3 : 4;
        const _Float16* bp = wlds + (lb * 16 + l15) * WSTR + q * 8;
#pragma unroll
        for (int ks = 0; ks < 7; ++ks) {
          f16x8 a = *(const f16x8*)(ap + ks * 32);
#pragma unroll
          for (int n = 0; n < 4; ++n) {
            if (n < cnt) {
              f16x8 b = *(const f16x8*)(bp + n * 16 * WSTR + ks * 32);
              acc[n] = __builtin_amdgcn_mfma_f32_16x16x32_f16(a, b, acc[n], 0, 0, 0);
            }
          }
        }
      }

      // ---- half 1: tiles 7..12 ----
      __syncthreads();  // all half-0 B reads done before overwrite
      {
        const _Float16* wg = g_wph + l * WELEMS + H0ROWS * WSTR;
        for (int c = tid; c < H1CH; c += 512) load_lds16(wg + c * 8, wlds + c * 8);
      }
      __syncthreads();  // drain
      {
        const int lb = cg ? 3 : 0;
        const int ao = cg ? 3 : 4;
        const _Float16* bp = wlds + (lb * 16 + l15) * WSTR + q * 8;
#pragma unroll
        for (int ks = 0; ks < 7; ++ks) {
          f16x8 a = *(const f16x8*)(ap + ks * 32);
#pragma unroll
          for (int n = 0; n < 3; ++n) {
            f16x8 b = *(const f16x8*)(bp + n * 16 * WSTR + ks * 32);
            acc[ao + n] = __builtin_amdgcn_mfma_f32_16x16x32_f16(a, b, acc[ao + n], 0, 0, 0);
          }
        }
      }
      __syncthreads();  // all act/wlds reads done before in-place act writes

      // epilogue: bias + relu, in-place fp16 (per-wave disjoint cols)
      const int cnt2 = cg ? 6 : 7;
#pragma unroll
      for (int i = 0; i < 7; ++i) {
        if (i < cnt2) {
          int gt = cg ? ((i < 3) ? 4 + i : 7 + i)    // 4,5,6,10,11,12
                      : ((i < 4) ? i : 3 + i);       // 0,1,2,3,7,8,9
          int ctile = gt * 16;
#pragma unroll
          for (int r = 0; r < 4; ++r) {
            int rr = (mode == 0) ? (q * 4 + r) : l15;
            int cc = (mode == 0) ? l15 : (q * 4 + r);
            int row = band * 16 + rr, col = ctile + cc;
            float v = acc[i][r] + ((col < HID) ? ldf(b_hid, l * HID + col, isbf) : 0.f);
            act[row * ASTR + col] = (_Float16)fmaxf(v, 0.f);
          }
        }
      }
    }

    __syncthreads();
    // Output layer: 8 threads/row x 25 cols
    {
      int m = tid >> 3, c = tid & 7;
      const _Float16* ar = act + m * ASTR;
      float s = 0.f;
#pragma unroll
      for (int j = c * 25; j < c * 25 + 25; ++j)
        s += (float)ar[j] * ldf(w_out, j, isbf);
      s += __shfl_down(s, 4);
      s += __shfl_down(s, 2);
      s += __shfl_down(s, 1);
      if (c == 0) {
        float logit = s + ldf(b_out, 0, isbf);
        float o = 1.f / (1.f + __expf(-logit));
        if (isbf) ((u16*)out)[nb + m] = f2bf(o);
        else ((float*)out)[nb + m] = o;
      }
    }
  } else {
    // ---- VALU fallback (defensive; 2 passes of 32 rows) ----
    float(*fA)[201] = (float(*)[201])smem;                    // 32x201 fp32
    float(*fB)[201] = (float(*)[201])(smem + 32 * 201 * 4);
    float* h0f = (float*)(smem + 64 * 201 * 4);
    for (int p = 0; p < 2; ++p) {
      __syncthreads();
      if (tid < 32) {
        int node = nb + p * 32 + tid;
        float a = 0.f;
#pragma unroll
        for (int r = 0; r < NREP; ++r) a += g_agg[(size_t)r * N_NODES + node];
        h0f[tid] = a * ldf(w_rel, 0, isbf) + ldf(b_rel, 0, isbf) +
                   g_xf[node] * ldf(w_root, 0, isbf);
      }
      __syncthreads();
      for (int i = tid; i < 32 * HID; i += 512) {
        int mm = i / HID, ff = i - mm * HID;
        float v = h0f[mm] * ldf(w_in, ff, isbf) + ldf(b_in, ff, isbf);
        fA[mm][ff] = v > 0.f ? v : 0.f;
      }
      __syncthreads();
      const int m = tid >> 4, c = tid & 15;
      float(*ain)[201] = fA;
      float(*aout)[201] = fB;
      for (int l = 0; l < 6; ++l) {
        float acc[13];
#pragma unroll
        for (int jj = 0; jj < 13; ++jj) {
          int j = c * 13 + jj;
          acc[jj] = (j < HID) ? ldf(b_hid, l * HID + j, isbf) : 0.f;
        }
        const float* wl = g_wf + l * HID * HID;
        for (int k = 0; k < HID; ++k) {
          float a = ain[m][k];
          const float* wr = wl + k * HID;
#pragma unroll
          for (int jj = 0; jj < 13; ++jj) {
            int j = c * 13 + jj;
            if (j < HID) acc[jj] = fmaf(a, wr[j], acc[jj]);
          }
        }
        __syncthreads();
#pragma unroll
        for (int jj = 0; jj < 13; ++jj) {
          int j = c * 13 + jj;
          if (j < HID) aout[m][j] = fmaxf(acc[jj], 0.f);
        }
        float(*tsw)[201] = ain; ain = aout; aout = tsw;
        __syncthreads();
      }
      float s = 0.f;
      for (int j = c * 13; j < c * 13 + 13 && j < HID; ++j)
        s += ain[m][j] * ldf(w_out, j, isbf);
      s += __shfl_down(s, 8);
      s += __shfl_down(s, 4);
      s += __shfl_down(s, 2);
      s += __shfl_down(s, 1);
      int node = nb + p * 32 + m;
      if (c == 0) {
        float logit = s + ldf(b_out, 0, isbf);
        float o = 1.f / (1.f + __expf(-logit));
        if (isbf) ((u16*)out)[node] = f2bf(o);
        else ((float*)out)[node] = o;
      }
    }
  }
}

extern "C" void kernel_launch(void* const* d_in, const int* in_sizes, int n_in,
                              void* d_out, int out_size, void* d_ws, size_t ws_size,
                              hipStream_t stream) {
  const void* x      = d_in[0];
  const int* ei      = (const int*)d_in[1];
  const void* w_rel  = d_in[2];
  const void* b_rel  = d_in[3];
  const void* w_root = d_in[4];
  const void* w_in   = d_in[5];
  const void* b_in   = d_in[6];
  const void* w_hid  = d_in[7];
  const void* b_hid  = d_in[8];
  const void* w_out  = d_in[9];
  const void* b_out  = d_in[10];
  (void)d_ws; (void)ws_size; (void)in_sizes; (void)n_in; (void)out_size;

  sniff_kernel<<<1, 64, 0, stream>>>((const u32*)x);
  prep_kernel<<<(NREP * N_NODES + 255) / 256, 256, 0, stream>>>(x, w_hid);
  scatter_kernel<<<N_EDGES / 8 / 256, 256, 0, stream>>>(ei);
  mlp_kernel<<<N_NODES / MT, 512, LDS_TOTAL, stream>>>(
      w_rel, b_rel, w_root, w_in, b_in, b_hid, w_out, b_out, d_out);
}

// Round 12
// 744.043 us; speedup vs baseline: 5.3785x; 5.3785x over previous
//
#include <hip/hip_runtime.h>

#define N_NODES 200000
#define N_EDGES 6400000
#define HID 200
#define NREP 8                    // scatter accumulator replicas
#define MT 64                     // nodes per block (3125 * 64 = 200000 exactly)
#define ASTR 232                  // act row stride (fp16): 464 B; 2-way bank alias = free
#define AELEM (MT * ASTR)         // 14848 elems = 29696 B
#define WSTR 232
#define WROWS 224
#define WELEMS (WROWS * WSTR)     // g_wph per-layer elems
#define H0ROWS 112                // half0: tiles 0..6
#define H1ROWS 96                 // half1: tiles 7..12
#define H0CH (H0ROWS * WSTR * 2 / 16)   // 3248 16-B chunks
#define H1CH (H1ROWS * WSTR * 2 / 16)   // 2784 16-B chunks

// LDS: act [0, 29696) ; wlds [29696, 81664) ; h0s aliased at wlds start (dead
// before first stage). 81,664 x 2 blocks = 163,328 <= 163,840 -> 2 blocks/CU.
#define LDS_WOFF 29696
#define LDS_TOTAL 81664

typedef float f32x4 __attribute__((ext_vector_type(4)));
typedef _Float16 f16x8 __attribute__((ext_vector_type(8)));
typedef unsigned short u16;
typedef unsigned int u32;

__device__ __align__(16) float g_agg[NREP * N_NODES];
__device__ __align__(16) float g_xf[N_NODES];            // fp32 copy of x
__device__ __align__(16) float g_wf[6 * HID * HID];      // fp32 (VALU fallback)
__device__ __align__(16) _Float16 g_wph[6 * WELEMS];     // fp16 W^T padded [l][n][k]
__device__ int g_isbf;

__device__ __forceinline__ float bf2f(u16 u) {
  union { u32 i; float f; } v; v.i = ((u32)u) << 16; return v.f;
}
__device__ __forceinline__ u16 f2bf(float f) {  // RNE
  u32 i = __float_as_uint(f);
  return (u16)((i + 0x7FFFu + ((i >> 16) & 1u)) >> 16);
}
__device__ __forceinline__ float ldf(const void* p, int i, int isbf) {
  return isbf ? bf2f(((const u16*)p)[i]) : ((const float*)p)[i];
}
__device__ __forceinline__ void load_lds16(const void* g, void* l) {
  __builtin_amdgcn_global_load_lds(
      (const __attribute__((address_space(1))) u32*)g,
      (__attribute__((address_space(3))) u32*)l, 16, 0, 0);
}

// ---- rank-2 MFMA layout self-test (fp16), reference folded at compile time ----
constexpr int tf1(int m) { return (m & 3) + 1; }
constexpr int tf2(int m) { return ((m >> 2) & 3) + 2; }
constexpr int tg1(int k) { return (k & 7) + 1; }
constexpr int tg2(int k) { return ((k >> 3) & 3) + 1; }
constexpr int tu1(int k) { return ((k * 3) & 7) + 1; }
constexpr int tu2(int k) { return ((k >> 2) & 3) + 2; }
constexpr int tw1(int n) { return ((n * 5) & 7) + 1; }
constexpr int tw2(int n) { return ((n >> 2) & 3) + 1; }
constexpr int calcS(int i, int j) {
  int s = 0;
  for (int k = 0; k < 32; ++k)
    s += (i ? tg2(k) : tg1(k)) * (j ? tu2(k) : tu1(k));
  return s;
}
__device__ __forceinline__ float refD(int m, int n) {
  constexpr int S11 = calcS(0, 0), S12 = calcS(0, 1), S21 = calcS(1, 0), S22 = calcS(1, 1);
  return (float)(tf1(m) * tw1(n) * S11 + tf1(m) * tw2(n) * S12 +
                 tf2(m) * tw1(n) * S21 + tf2(m) * tw2(n) * S22);
}
__device__ int mfma_selftest(int l15, int q) {
  f16x8 av, bv;
#pragma unroll
  for (int j = 0; j < 8; ++j) {
    int k = q * 8 + j;
    av[j] = (_Float16)(float)(tf1(l15) * tg1(k) + tf2(l15) * tg2(k));
    bv[j] = (_Float16)(float)(tu1(k) * tw1(l15) + tu2(k) * tw2(l15));
  }
  f32x4 d = __builtin_amdgcn_mfma_f32_16x16x32_f16(av, bv, (f32x4){0.f, 0.f, 0.f, 0.f}, 0, 0, 0);
  bool ok0 = true, ok1 = true;
#pragma unroll
  for (int r = 0; r < 4; ++r) {
    ok0 = ok0 && (d[r] == refD(q * 4 + r, l15));
    ok1 = ok1 && (d[r] == refD(l15, q * 4 + r));
  }
  return __all(ok0) ? 0 : (__all(ok1) ? 1 : 2);
}

// ---- K0: dtype sniff ----
__global__ void sniff_kernel(const u32* __restrict__ xw) {
  int i = threadIdx.x;  // 64 threads
  u32 e = (xw[i] >> 7) & 0xFFu;
  unsigned long long b = __ballot(e >= 110u && e <= 135u);
  if (i == 0) g_isbf = (__popcll(b) >= 48) ? 1 : 0;
}

// ---- K1: zero replicas + fp32 x + both weight forms ----
__global__ void prep_kernel(const void* __restrict__ x, const void* __restrict__ w_hid) {
  int t = blockIdx.x * blockDim.x + threadIdx.x;   // 1.6M threads
  int isbf = g_isbf;
  if (t < NREP * N_NODES) g_agg[t] = 0.f;
  if (t < N_NODES) g_xf[t] = ldf(x, t, isbf);
  if (t < 6 * HID * HID) g_wf[t] = ldf(w_hid, t, isbf);
  if (t < 6 * WELEMS) {
    int l = t / WELEMS;
    int r = t - l * WELEMS;
    int n = r / WSTR;
    int k = r - n * WSTR;
    float v = 0.f;
    if (n < HID && k < HID) v = ldf(w_hid, (l * HID + k) * HID + n, isbf);
    g_wph[t] = (_Float16)v;
  }
}

// ---- K2: edge scatter-add; 8 edges/thread, batched loads, 8 replicas ----
__global__ void scatter_kernel(const int* __restrict__ ei) {
  int t = blockIdx.x * blockDim.x + threadIdx.x;   // 800K threads
  int e = t * 8;
  float* agg = g_agg + (size_t)(blockIdx.x & (NREP - 1)) * N_NODES;
  bool is64 = ((ei[1] | ei[3] | ei[5] | ei[7]) == 0);
  int s[8], d[8];
  if (is64) {
#pragma unroll
    for (int i = 0; i < 4; ++i) {
      int4 a = *(const int4*)(ei + 2 * e + 4 * i);
      int4 b = *(const int4*)(ei + 2 * N_EDGES + 2 * e + 4 * i);
      s[2 * i] = a.x; s[2 * i + 1] = a.z;
      d[2 * i] = b.x; d[2 * i + 1] = b.z;
    }
  } else {
#pragma unroll
    for (int i = 0; i < 2; ++i) {
      int4 a = *(const int4*)(ei + e + 4 * i);
      int4 b = *(const int4*)(ei + N_EDGES + e + 4 * i);
      s[4 * i] = a.x; s[4 * i + 1] = a.y; s[4 * i + 2] = a.z; s[4 * i + 3] = a.w;
      d[4 * i] = b.x; d[4 * i + 1] = b.y; d[4 * i + 2] = b.z; d[4 * i + 3] = b.w;
    }
  }
  float v[8];
#pragma unroll
  for (int i = 0; i < 8; ++i) v[i] = g_xf[s[i]];
#pragma unroll
  for (int i = 0; i < 8; ++i) atomicAdd(&agg[d[i]], v[i]);
}

// ---- K3: fused MLP; MT=64, 512 thr / 8 waves, W in halves -> 2 blocks/CU ----
// __launch_bounds__(512, 4): B=512 -> k blocks/CU = w/2, so w=4 targets 2
// blocks/CU (R11 used w=2 = 1 block/CU). ALL acc[] indices are literals:
// R11's acc[ao+n] runtime index demoted acc to scratch/movrel (VALUBusy 89%).
__global__ __launch_bounds__(512, 4) void mlp_kernel(
    const void* __restrict__ w_rel, const void* __restrict__ b_rel, const void* __restrict__ w_root,
    const void* __restrict__ w_in, const void* __restrict__ b_in,
    const void* __restrict__ b_hid, const void* __restrict__ w_out, const void* __restrict__ b_out,
    void* __restrict__ out) {
  extern __shared__ char smem[];
  _Float16* act = (_Float16*)smem;
  _Float16* wlds = (_Float16*)(smem + LDS_WOFF);
  float* h0s = (float*)(smem + LDS_WOFF);  // aliased; dead before first stage

  const int tid = threadIdx.x;
  const int nb = blockIdx.x * MT;
  const int isbf = g_isbf;
  const int lane = tid & 63;
  const int wv = tid >> 6;          // 8 waves
  const int l15 = lane & 15;
  const int q = lane >> 4;
  const int band = wv >> 1;         // 4 bands x 16 rows
  const int cg = wv & 1;            // col group (wave-uniform)

  const int mode = mfma_selftest(l15, q);

  // GraphConv h0 (8 replicas summed)
  if (tid < MT) {
    int node = nb + tid;
    float a = 0.f;
#pragma unroll
    for (int r = 0; r < NREP; ++r) a += g_agg[(size_t)r * N_NODES + node];
    h0s[tid] = a * ldf(w_rel, 0, isbf) + ldf(b_rel, 0, isbf) +
               g_xf[node] * ldf(w_root, 0, isbf);
  }
  __syncthreads();

  if (mode < 2) {
    // Input layer: act[m][j] = relu(h0[m]*w_in[j]+b_in[j]); pad cols zeroed
    for (int idx = tid; idx < AELEM; idx += 512) {
      int m = idx / ASTR, j = idx - m * ASTR;
      float v = 0.f;
      if (j < HID) {
        v = h0s[m] * ldf(w_in, j, isbf) + ldf(b_in, j, isbf);
        v = fmaxf(v, 0.f);
      }
      act[idx] = (_Float16)v;
    }

    for (int l = 0; l < 6; ++l) {
      f32x4 acc[7];
#pragma unroll
      for (int n = 0; n < 7; ++n) acc[n] = (f32x4){0.f, 0.f, 0.f, 0.f};

      const _Float16* ap = act + (band * 16 + l15) * ASTR + q * 8;

      // ---- half 0: global tiles 0..6 staged at local rows 0..111 ----
      __syncthreads();  // act stable, prior wlds reads done
      {
        const _Float16* wg = g_wph + l * WELEMS;
        for (int c = tid; c < H0CH; c += 512) load_lds16(wg + c * 8, wlds + c * 8);
      }
      __syncthreads();  // drain
      if (cg == 0) {    // tiles 0..3 -> acc[0..3] (all indices literal)
        const _Float16* bp = wlds + l15 * WSTR + q * 8;
#pragma unroll
        for (int ks = 0; ks < 7; ++ks) {
          f16x8 a = *(const f16x8*)(ap + ks * 32);
#pragma unroll
          for (int n = 0; n < 4; ++n) {
            f16x8 b = *(const f16x8*)(bp + n * 16 * WSTR + ks * 32);
            acc[n] = __builtin_amdgcn_mfma_f32_16x16x32_f16(a, b, acc[n], 0, 0, 0);
          }
        }
      } else {          // tiles 4..6 -> acc[0..2]
        const _Float16* bp = wlds + (4 * 16 + l15) * WSTR + q * 8;
#pragma unroll
        for (int ks = 0; ks < 7; ++ks) {
          f16x8 a = *(const f16x8*)(ap + ks * 32);
#pragma unroll
          for (int n = 0; n < 3; ++n) {
            f16x8 b = *(const f16x8*)(bp + n * 16 * WSTR + ks * 32);
            acc[n] = __builtin_amdgcn_mfma_f32_16x16x32_f16(a, b, acc[n], 0, 0, 0);
          }
        }
      }

      // ---- half 1: global tiles 7..12 staged at local rows 0..95 ----
      __syncthreads();  // all half-0 B reads done before overwrite
      {
        const _Float16* wg = g_wph + l * WELEMS + H0ROWS * WSTR;
        for (int c = tid; c < H1CH; c += 512) load_lds16(wg + c * 8, wlds + c * 8);
      }
      __syncthreads();  // drain
      if (cg == 0) {    // tiles 7..9 -> acc[4..6]
        const _Float16* bp = wlds + l15 * WSTR + q * 8;
#pragma unroll
        for (int ks = 0; ks < 7; ++ks) {
          f16x8 a = *(const f16x8*)(ap + ks * 32);
#pragma unroll
          for (int n = 0; n < 3; ++n) {
            f16x8 b = *(const f16x8*)(bp + n * 16 * WSTR + ks * 32);
            acc[4 + n] = __builtin_amdgcn_mfma_f32_16x16x32_f16(a, b, acc[4 + n], 0, 0, 0);
          }
        }
      } else {          // tiles 10..12 -> acc[3..5]
        const _Float16* bp = wlds + (3 * 16 + l15) * WSTR + q * 8;
#pragma unroll
        for (int ks = 0; ks < 7; ++ks) {
          f16x8 a = *(const f16x8*)(ap + ks * 32);
#pragma unroll
          for (int n = 0; n < 3; ++n) {
            f16x8 b = *(const f16x8*)(bp + n * 16 * WSTR + ks * 32);
            acc[3 + n] = __builtin_amdgcn_mfma_f32_16x16x32_f16(a, b, acc[3 + n], 0, 0, 0);
          }
        }
      }
      __syncthreads();  // all act/wlds reads done before in-place act writes

      // epilogue: bias + relu, in-place fp16 (all acc indices literal)
      if (cg == 0) {    // acc[0..3]->tiles 0..3, acc[4..6]->tiles 7..9
#pragma unroll
        for (int i = 0; i < 7; ++i) {
          const int gt = (i < 4) ? i : 3 + i;   // 0,1,2,3,7,8,9 (i literal)
          const int ctile = gt * 16;
#pragma unroll
          for (int r = 0; r < 4; ++r) {
            int rr = (mode == 0) ? (q * 4 + r) : l15;
            int cc = (mode == 0) ? l15 : (q * 4 + r);
            int row = band * 16 + rr, col = ctile + cc;
            float v = acc[i][r] + ((col < HID) ? ldf(b_hid, l * HID + col, isbf) : 0.f);
            act[row * ASTR + col] = (_Float16)fmaxf(v, 0.f);
          }
        }
      } else {          // acc[0..2]->tiles 4..6, acc[3..5]->tiles 10..12
#pragma unroll
        for (int i = 0; i < 6; ++i) {
          const int gt = (i < 3) ? 4 + i : 7 + i;  // 4,5,6,10,11,12
          const int ctile = gt * 16;
#pragma unroll
          for (int r = 0; r < 4; ++r) {
            int rr = (mode == 0) ? (q * 4 + r) : l15;
            int cc = (mode == 0) ? l15 : (q * 4 + r);
            int row = band * 16 + rr, col = ctile + cc;
            float v = acc[i][r] + ((col < HID) ? ldf(b_hid, l * HID + col, isbf) : 0.f);
            act[row * ASTR + col] = (_Float16)fmaxf(v, 0.f);
          }
        }
      }
    }

    __syncthreads();
    // Output layer: 8 threads/row x 25 cols
    {
      int m = tid >> 3, c = tid & 7;
      const _Float16* ar = act + m * ASTR;
      float s = 0.f;
#pragma unroll
      for (int j = c * 25; j < c * 25 + 25; ++j)
        s += (float)ar[j] * ldf(w_out, j, isbf);
      s += __shfl_down(s, 4);
      s += __shfl_down(s, 2);
      s += __shfl_down(s, 1);
      if (c == 0) {
        float logit = s + ldf(b_out, 0, isbf);
        float o = 1.f / (1.f + __expf(-logit));
        if (isbf) ((u16*)out)[nb + m] = f2bf(o);
        else ((float*)out)[nb + m] = o;
      }
    }
  } else {
    // ---- VALU fallback (defensive; 2 passes of 32 rows) ----
    float(*fA)[201] = (float(*)[201])smem;                    // 32x201 fp32
    float(*fB)[201] = (float(*)[201])(smem + 32 * 201 * 4);
    float* h0f = (float*)(smem + 64 * 201 * 4);
    for (int p = 0; p < 2; ++p) {
      __syncthreads();
      if (tid < 32) {
        int node = nb + p * 32 + tid;
        float a = 0.f;
#pragma unroll
        for (int r = 0; r < NREP; ++r) a += g_agg[(size_t)r * N_NODES + node];
        h0f[tid] = a * ldf(w_rel, 0, isbf) + ldf(b_rel, 0, isbf) +
                   g_xf[node] * ldf(w_root, 0, isbf);
      }
      __syncthreads();
      for (int i = tid; i < 32 * HID; i += 512) {
        int mm = i / HID, ff = i - mm * HID;
        float v = h0f[mm] * ldf(w_in, ff, isbf) + ldf(b_in, ff, isbf);
        fA[mm][ff] = v > 0.f ? v : 0.f;
      }
      __syncthreads();
      const int m = tid >> 4, c = tid & 15;
      float(*ain)[201] = fA;
      float(*aout)[201] = fB;
      for (int l = 0; l < 6; ++l) {
        float acc[13];
#pragma unroll
        for (int jj = 0; jj < 13; ++jj) {
          int j = c * 13 + jj;
          acc[jj] = (j < HID) ? ldf(b_hid, l * HID + j, isbf) : 0.f;
        }
        const float* wl = g_wf + l * HID * HID;
        for (int k = 0; k < HID; ++k) {
          float a = ain[m][k];
          const float* wr = wl + k * HID;
#pragma unroll
          for (int jj = 0; jj < 13; ++jj) {
            int j = c * 13 + jj;
            if (j < HID) acc[jj] = fmaf(a, wr[j], acc[jj]);
          }
        }
        __syncthreads();
#pragma unroll
        for (int jj = 0; jj < 13; ++jj) {
          int j = c * 13 + jj;
          if (j < HID) aout[m][j] = fmaxf(acc[jj], 0.f);
        }
        float(*tsw)[201] = ain; ain = aout; aout = tsw;
        __syncthreads();
      }
      float s = 0.f;
      for (int j = c * 13; j < c * 13 + 13 && j < HID; ++j)
        s += ain[m][j] * ldf(w_out, j, isbf);
      s += __shfl_down(s, 8);
      s += __shfl_down(s, 4);
      s += __shfl_down(s, 2);
      s += __shfl_down(s, 1);
      int node = nb + p * 32 + m;
      if (c == 0) {
        float logit = s + ldf(b_out, 0, isbf);
        float o = 1.f / (1.f + __expf(-logit));
        if (isbf) ((u16*)out)[node] = f2bf(o);
        else ((float*)out)[node] = o;
      }
    }
  }
}

extern "C" void kernel_launch(void* const* d_in, const int* in_sizes, int n_in,
                              void* d_out, int out_size, void* d_ws, size_t ws_size,
                              hipStream_t stream) {
  const void* x      = d_in[0];
  const int* ei      = (const int*)d_in[1];
  const void* w_rel  = d_in[2];
  const void* b_rel  = d_in[3];
  const void* w_root = d_in[4];
  const void* w_in   = d_in[5];
  const void* b_in   = d_in[6];
  const void* w_hid  = d_in[7];
  const void* b_hid  = d_in[8];
  const void* w_out  = d_in[9];
  const void* b_out  = d_in[10];
  (void)d_ws; (void)ws_size; (void)in_sizes; (void)n_in; (void)out_size;

  sniff_kernel<<<1, 64, 0, stream>>>((const u32*)x);
  prep_kernel<<<(NREP * N_NODES + 255) / 256, 256, 0, stream>>>(x, w_hid);
  scatter_kernel<<<N_EDGES / 8 / 256, 256, 0, stream>>>(ei);
  mlp_kernel<<<N_NODES / MT, 512, LDS_TOTAL, stream>>>(
      w_rel, b_rel, w_root, w_in, b_in, b_hid, w_out, b_out, d_out);
}